// Round 11
// baseline (38.392 us; speedup 1.0000x reference)
//
#include <hip/hip_runtime.h>
#include <math.h>

#define BB 4
#define SS 4096
#define HH 2048
#define DD 3
#define KK 1365            // max(1, int(4096/3))
#define ONEBITS 0x3f800000u
#define NBLK 4096          // 4 waves/block, 1 token/wave

typedef float f32x4 __attribute__((ext_vector_type(4)));   // native vec for nt builtins

// ---------------- Kernel A: scores + loss partials + m0 ones ----------------
// R8's verified structure (best: 30.50us) with NON-TEMPORAL loads on the hs
// stream: hs has zero reuse, so skip L2/L3 allocation on it (nt flag) to keep
// the read path free of allocate/evict machinery. Values and accumulation
// order bit-identical to R8 -> scores exact -> selection exact.
__global__ __launch_bounds__(256) void score_kernel(
    const float* __restrict__ hs, const float* __restrict__ theta,
    float* __restrict__ scores0, double* __restrict__ partials,
    float* __restrict__ m0)
{
    // masks[0] is all-ones, data-independent: spread the 64 KB write here.
    const long gid = (long)blockIdx.x * 256 + threadIdx.x;
    if (gid < (long)BB * SS) __builtin_nontemporal_store(1.0f, &m0[gid]);

    const int wave = threadIdx.x >> 6;
    const int lane = threadIdx.x & 63;
    const long token = (long)blockIdx.x * 4 + wave;

    const f32x4* row = reinterpret_cast<const f32x4*>(hs + token * HH);
    const float4* t0p = reinterpret_cast<const float4*>(theta);
    const float4* t1p = reinterpret_cast<const float4*>(theta + HH);
    const float4* t2p = reinterpret_cast<const float4*>(theta + 2 * HH);

    // 4-deep prefetch window on the hs stream, non-temporal
    f32x4 h0 = __builtin_nontemporal_load(row + 0 * 64 + lane);
    f32x4 h1 = __builtin_nontemporal_load(row + 1 * 64 + lane);
    f32x4 h2 = __builtin_nontemporal_load(row + 2 * 64 + lane);
    f32x4 h3 = __builtin_nontemporal_load(row + 3 * 64 + lane);

    float a0 = 0.0f, a1 = 0.0f, a2 = 0.0f;

#define COMP(hj, j) {                                               \
        const int v = (j) * 64 + lane;                              \
        const float4 x0 = t0p[v];                                   \
        const float4 x1 = t1p[v];                                   \
        const float4 x2 = t2p[v];                                   \
        a0 += hj[0] * x0.x + hj[1] * x0.y + hj[2] * x0.z + hj[3] * x0.w; \
        a1 += hj[0] * x1.x + hj[1] * x1.y + hj[2] * x1.z + hj[3] * x1.w; \
        a2 += hj[0] * x2.x + hj[1] * x2.y + hj[2] * x2.z + hj[3] * x2.w; \
    }

    f32x4 h4 = __builtin_nontemporal_load(row + 4 * 64 + lane);  COMP(h0, 0)
    f32x4 h5 = __builtin_nontemporal_load(row + 5 * 64 + lane);  COMP(h1, 1)
    f32x4 h6 = __builtin_nontemporal_load(row + 6 * 64 + lane);  COMP(h2, 2)
    f32x4 h7 = __builtin_nontemporal_load(row + 7 * 64 + lane);  COMP(h3, 3)
    COMP(h4, 4)
    COMP(h5, 5)
    COMP(h6, 6)
    COMP(h7, 7)
#undef COMP

#pragma unroll
    for (int off = 32; off; off >>= 1) {
        a0 += __shfl_down(a0, off);
        a1 += __shfl_down(a1, off);
        a2 += __shfl_down(a2, off);
    }

    __shared__ double wpart[4][DD];
    if (lane == 0) {
        const float s0 = 1.0f / (1.0f + expf(-a0));
        const float s1 = 1.0f / (1.0f + expf(-a1));
        const float s2 = 1.0f / (1.0f + expf(-a2));
        scores0[token] = s0;           // re-read by select: keep cacheable
        wpart[wave][0] = (double)(1.0f / (1.0f + expf(-s0)));
        wpart[wave][1] = (double)(1.0f / (1.0f + expf(-s1)));
        wpart[wave][2] = (double)(1.0f / (1.0f + expf(-s2)));
    }
    __syncthreads();
    if (threadIdx.x < DD)
        partials[(long)blockIdx.x * DD + threadIdx.x] =
            wpart[0][threadIdx.x] + wpart[1][threadIdx.x] +
            wpart[2][threadIdx.x] + wpart[3][threadIdx.x];
}

// ---------------- Kernel B: selection (12 blocks) + loss (block 12) ---------
// Verbatim R2-verified. Blocks 0..11: (row b = blk/3, plane = blk%3).
// Fast path: if count(score==1.0f) >= k, selection = first k ones.
// Fallback: exact 4x8-bit radix select, block-uniform.
__global__ __launch_bounds__(1024) void select_kernel(
    const float* __restrict__ scores0, const double* __restrict__ partials,
    float* __restrict__ out)
{
    const int tid  = threadIdx.x;
    const int lane = tid & 63;
    const int wid  = tid >> 6;
    const int blk  = blockIdx.x;

    if (blk == 12) {   // ---- balancing loss ----
        double a0 = 0.0, a1 = 0.0, a2 = 0.0;
        for (int i = tid; i < NBLK; i += 1024) {
            a0 += partials[(long)i * DD + 0];
            a1 += partials[(long)i * DD + 1];
            a2 += partials[(long)i * DD + 2];
        }
#pragma unroll
        for (int off = 32; off; off >>= 1) {
            a0 += __shfl_down(a0, off);
            a1 += __shfl_down(a1, off);
            a2 += __shfl_down(a2, off);
        }
        __shared__ double shl[DD][16];
        if (lane == 0) { shl[0][wid] = a0; shl[1][wid] = a1; shl[2][wid] = a2; }
        __syncthreads();
        if (tid == 0) {
            double p0 = 0, p1 = 0, p2 = 0;
            for (int w = 0; w < 16; ++w) { p0 += shl[0][w]; p1 += shl[1][w]; p2 += shl[2][w]; }
            const double n = (double)BB * SS;
            p0 /= n; p1 /= n; p2 /= n;
            const double t = 1.0 / 3.0;
            out[(long)BB * SS] = (float)((t * (log(t) - log(p0)) +
                                          t * (log(t) - log(p1)) +
                                          t * (log(t) - log(p2))) / 3.0);
        }
        return;
    }

    const int b = blk / 3, plane = blk % 3;
    const float* rowp = scores0 + (long)b * SS;

    __shared__ unsigned wsum[16];
    __shared__ __align__(16) unsigned su[SS];   // fallback only
    __shared__ unsigned whist[16 * 256];        // fallback only
    __shared__ unsigned wtot[4];
    __shared__ unsigned sbin, skk;

    uint4 uu = reinterpret_cast<const uint4*>(rowp)[tid];

    unsigned vstar = ONEBITS;
    unsigned e0 = (uu.x == vstar), e1 = (uu.y == vstar),
             e2 = (uu.z == vstar), e3 = (uu.w == vstar);
    unsigned cnt = e0 + e1 + e2 + e3;

    // block exclusive scan of cnt (also yields block total)
    unsigned inc = cnt;
#pragma unroll
    for (int off = 1; off < 64; off <<= 1) {
        unsigned t = __shfl_up(inc, off);
        if (lane >= off) inc += t;
    }
    if (lane == 63) wsum[wid] = inc;
    __syncthreads();
    if (wid == 0) {
        unsigned wv = (lane < 16) ? wsum[lane] : 0;
#pragma unroll
        for (int off = 1; off < 16; off <<= 1) {
            unsigned t = __shfl_up(wv, off);
            if (lane >= off) wv += t;
        }
        if (lane < 16) wsum[lane] = wv;
    }
    __syncthreads();
    unsigned p     = inc - cnt + (wid > 0 ? wsum[wid - 1] : 0);
    unsigned total = wsum[15];
    unsigned rem   = KK;

    if (total < KK) {   // ---- block-uniform fallback: exact radix select ----
        for (int i = tid; i < SS; i += 1024) su[i] = __float_as_uint(rowp[i]);
        unsigned prefix = 0, maskbits = 0, kk = KK;
        for (int pass = 0; pass < 4; ++pass) {
            const int shift = 24 - 8 * pass;
            for (int i = tid; i < 16 * 256; i += 1024) whist[i] = 0;
            __syncthreads();
            for (int i = tid; i < SS; i += 1024) {
                unsigned u = su[i];
                if ((u & maskbits) == prefix)
                    atomicAdd(&whist[(wid << 8) + ((u >> shift) & 255u)], 1u);
            }
            __syncthreads();
            unsigned val = 0, s = 0;
            if (tid < 256) {
                for (int w = 0; w < 16; ++w) val += whist[(w << 8) + tid];
                s = val;
#pragma unroll
                for (int off = 1; off < 64; off <<= 1) {
                    unsigned t = __shfl_down(s, off);
                    if (lane + off < 64) s += t;
                }
                if (lane == 0) wtot[wid] = s;
            }
            __syncthreads();
            if (tid < 256) {
                unsigned cge = s;
                for (int w = wid + 1; w < 4; ++w) cge += wtot[w];
                unsigned cgt = cge - val;
                if (cgt < kk && cge >= kk) { sbin = (unsigned)tid; skk = kk - cgt; }
            }
            __syncthreads();
            prefix   |= (sbin << shift);
            maskbits |= (255u << shift);
            kk = skk;
        }
        vstar = prefix;
        rem   = kk;
        e0 = (uu.x == vstar); e1 = (uu.y == vstar);
        e2 = (uu.z == vstar); e3 = (uu.w == vstar);
        cnt = e0 + e1 + e2 + e3;
        inc = cnt;
#pragma unroll
        for (int off = 1; off < 64; off <<= 1) {
            unsigned t = __shfl_up(inc, off);
            if (lane >= off) inc += t;
        }
        __syncthreads();   // protect wsum reuse
        if (lane == 63) wsum[wid] = inc;
        __syncthreads();
        if (wid == 0) {
            unsigned wv = (lane < 16) ? wsum[lane] : 0;
#pragma unroll
            for (int off = 1; off < 16; off <<= 1) {
                unsigned t = __shfl_up(wv, off);
                if (lane >= off) wv += t;
            }
            if (lane < 16) wsum[lane] = wv;
        }
        __syncthreads();
        p = inc - cnt + (wid > 0 ? wsum[wid - 1] : 0);
    }

    // selection: strictly-greater always in; ties by lowest index
    const bool sel0 = (uu.x > vstar) || (e0 && p < rem); p += e0;
    const bool sel1 = (uu.y > vstar) || (e1 && p < rem); p += e1;
    const bool sel2 = (uu.z > vstar) || (e2 && p < rem); p += e2;
    const bool sel3 = (uu.w > vstar) || (e3 && p < rem);

    if (plane == 0) {
        float4 dv = make_float4(sel0 ? 3.0f : 1.0f, sel1 ? 3.0f : 1.0f,
                                sel2 ? 3.0f : 1.0f, sel3 ? 3.0f : 1.0f);
        reinterpret_cast<float4*>(out + (long)b * SS)[tid] = dv;
    } else {
        // masks base is out + B*S + 1 (odd float offset -> scalar stores)
        float* m = out + (long)BB * SS + 1 + (long)plane * BB * SS + (long)b * SS;
        const int base = tid * 4;
        m[base + 0] = sel0 ? 1.0f : 0.0f;
        m[base + 1] = sel1 ? 1.0f : 0.0f;
        m[base + 2] = sel2 ? 1.0f : 0.0f;
        m[base + 3] = sel3 ? 1.0f : 0.0f;
    }
}

extern "C" void kernel_launch(void* const* d_in, const int* in_sizes, int n_in,
                              void* d_out, int out_size, void* d_ws, size_t ws_size,
                              hipStream_t stream) {
    const float* hs    = (const float*)d_in[0];
    const float* theta = (const float*)d_in[1];
    float* out = (float*)d_out;

    float*  scores0  = (float*)d_ws;                                  // 64 KB
    double* partials = (double*)((char*)d_ws + (size_t)BB * SS * 4);  // 96 KB
    float*  m0       = out + (long)BB * SS + 1;                       // masks[0]

    score_kernel <<<dim3(NBLK), dim3(256),  0, stream>>>(hs, theta, scores0, partials, m0);
    select_kernel<<<dim3(13),   dim3(1024), 0, stream>>>(scores0, partials, out);
}

// Round 12
// 30.518 us; speedup vs baseline: 1.2580x; 1.2580x over previous
//
#include <hip/hip_runtime.h>
#include <math.h>

#define BB 4
#define SS 4096
#define HH 2048
#define DD 3
#define KK 1365            // max(1, int(4096/3))
#define ONEBITS 0x3f800000u
#define NBLK 4096          // 4 waves/block, 1 token/wave

// ---------------- Kernel A: scores + loss partials + m0 ones ----------------
// R8's verified structure — best of all 11 rounds (30.50us). 4-deep rotating
// prefetch on the hs stream, cacheable loads (R11 proved hs is ~half
// L3-resident during replays; nt loads that bypass L3 cost +8us).
// f32 accumulation (R7 verified selection-exact, absmax 0.0).
__global__ __launch_bounds__(256) void score_kernel(
    const float* __restrict__ hs, const float* __restrict__ theta,
    float* __restrict__ scores0, double* __restrict__ partials,
    float* __restrict__ m0)
{
    // masks[0] is all-ones, data-independent: spread the 64 KB write here.
    const long gid = (long)blockIdx.x * 256 + threadIdx.x;
    if (gid < (long)BB * SS) m0[gid] = 1.0f;

    const int wave = threadIdx.x >> 6;
    const int lane = threadIdx.x & 63;
    const long token = (long)blockIdx.x * 4 + wave;

    const float4* row = reinterpret_cast<const float4*>(hs + token * HH);
    const float4* t0p = reinterpret_cast<const float4*>(theta);
    const float4* t1p = reinterpret_cast<const float4*>(theta + HH);
    const float4* t2p = reinterpret_cast<const float4*>(theta + 2 * HH);

    // 4-deep prefetch window on the hs stream
    float4 h0 = row[0 * 64 + lane];
    float4 h1 = row[1 * 64 + lane];
    float4 h2 = row[2 * 64 + lane];
    float4 h3 = row[3 * 64 + lane];

    float a0 = 0.0f, a1 = 0.0f, a2 = 0.0f;

#define COMP(hj, j) {                                               \
        const int v = (j) * 64 + lane;                              \
        const float4 x0 = t0p[v];                                   \
        const float4 x1 = t1p[v];                                   \
        const float4 x2 = t2p[v];                                   \
        a0 += hj.x * x0.x + hj.y * x0.y + hj.z * x0.z + hj.w * x0.w; \
        a1 += hj.x * x1.x + hj.y * x1.y + hj.z * x1.z + hj.w * x1.w; \
        a2 += hj.x * x2.x + hj.y * x2.y + hj.z * x2.z + hj.w * x2.w; \
    }

    float4 h4 = row[4 * 64 + lane];  COMP(h0, 0)
    float4 h5 = row[5 * 64 + lane];  COMP(h1, 1)
    float4 h6 = row[6 * 64 + lane];  COMP(h2, 2)
    float4 h7 = row[7 * 64 + lane];  COMP(h3, 3)
    COMP(h4, 4)
    COMP(h5, 5)
    COMP(h6, 6)
    COMP(h7, 7)
#undef COMP

#pragma unroll
    for (int off = 32; off; off >>= 1) {
        a0 += __shfl_down(a0, off);
        a1 += __shfl_down(a1, off);
        a2 += __shfl_down(a2, off);
    }

    __shared__ double wpart[4][DD];
    if (lane == 0) {
        const float s0 = 1.0f / (1.0f + expf(-a0));
        const float s1 = 1.0f / (1.0f + expf(-a1));
        const float s2 = 1.0f / (1.0f + expf(-a2));
        scores0[token] = s0;
        // loss uses sigmoid applied twice (f64 partials, once/token)
        wpart[wave][0] = (double)(1.0f / (1.0f + expf(-s0)));
        wpart[wave][1] = (double)(1.0f / (1.0f + expf(-s1)));
        wpart[wave][2] = (double)(1.0f / (1.0f + expf(-s2)));
    }
    __syncthreads();
    if (threadIdx.x < DD)
        partials[(long)blockIdx.x * DD + threadIdx.x] =
            wpart[0][threadIdx.x] + wpart[1][threadIdx.x] +
            wpart[2][threadIdx.x] + wpart[3][threadIdx.x];
}

// ---------------- Kernel B: selection (12 blocks) + loss (block 12) ---------
// Verbatim R2-verified. Blocks 0..11: (row b = blk/3, plane = blk%3).
// Fast path: if count(score==1.0f) >= k, selection = first k ones.
// Fallback: exact 4x8-bit radix select, block-uniform.
__global__ __launch_bounds__(1024) void select_kernel(
    const float* __restrict__ scores0, const double* __restrict__ partials,
    float* __restrict__ out)
{
    const int tid  = threadIdx.x;
    const int lane = tid & 63;
    const int wid  = tid >> 6;
    const int blk  = blockIdx.x;

    if (blk == 12) {   // ---- balancing loss ----
        double a0 = 0.0, a1 = 0.0, a2 = 0.0;
        for (int i = tid; i < NBLK; i += 1024) {
            a0 += partials[(long)i * DD + 0];
            a1 += partials[(long)i * DD + 1];
            a2 += partials[(long)i * DD + 2];
        }
#pragma unroll
        for (int off = 32; off; off >>= 1) {
            a0 += __shfl_down(a0, off);
            a1 += __shfl_down(a1, off);
            a2 += __shfl_down(a2, off);
        }
        __shared__ double shl[DD][16];
        if (lane == 0) { shl[0][wid] = a0; shl[1][wid] = a1; shl[2][wid] = a2; }
        __syncthreads();
        if (tid == 0) {
            double p0 = 0, p1 = 0, p2 = 0;
            for (int w = 0; w < 16; ++w) { p0 += shl[0][w]; p1 += shl[1][w]; p2 += shl[2][w]; }
            const double n = (double)BB * SS;
            p0 /= n; p1 /= n; p2 /= n;
            const double t = 1.0 / 3.0;
            out[(long)BB * SS] = (float)((t * (log(t) - log(p0)) +
                                          t * (log(t) - log(p1)) +
                                          t * (log(t) - log(p2))) / 3.0);
        }
        return;
    }

    const int b = blk / 3, plane = blk % 3;
    const float* rowp = scores0 + (long)b * SS;

    __shared__ unsigned wsum[16];
    __shared__ __align__(16) unsigned su[SS];   // fallback only
    __shared__ unsigned whist[16 * 256];        // fallback only
    __shared__ unsigned wtot[4];
    __shared__ unsigned sbin, skk;

    uint4 uu = reinterpret_cast<const uint4*>(rowp)[tid];

    unsigned vstar = ONEBITS;
    unsigned e0 = (uu.x == vstar), e1 = (uu.y == vstar),
             e2 = (uu.z == vstar), e3 = (uu.w == vstar);
    unsigned cnt = e0 + e1 + e2 + e3;

    // block exclusive scan of cnt (also yields block total)
    unsigned inc = cnt;
#pragma unroll
    for (int off = 1; off < 64; off <<= 1) {
        unsigned t = __shfl_up(inc, off);
        if (lane >= off) inc += t;
    }
    if (lane == 63) wsum[wid] = inc;
    __syncthreads();
    if (wid == 0) {
        unsigned wv = (lane < 16) ? wsum[lane] : 0;
#pragma unroll
        for (int off = 1; off < 16; off <<= 1) {
            unsigned t = __shfl_up(wv, off);
            if (lane >= off) wv += t;
        }
        if (lane < 16) wsum[lane] = wv;
    }
    __syncthreads();
    unsigned p     = inc - cnt + (wid > 0 ? wsum[wid - 1] : 0);
    unsigned total = wsum[15];
    unsigned rem   = KK;

    if (total < KK) {   // ---- block-uniform fallback: exact radix select ----
        for (int i = tid; i < SS; i += 1024) su[i] = __float_as_uint(rowp[i]);
        unsigned prefix = 0, maskbits = 0, kk = KK;
        for (int pass = 0; pass < 4; ++pass) {
            const int shift = 24 - 8 * pass;
            for (int i = tid; i < 16 * 256; i += 1024) whist[i] = 0;
            __syncthreads();
            for (int i = tid; i < SS; i += 1024) {
                unsigned u = su[i];
                if ((u & maskbits) == prefix)
                    atomicAdd(&whist[(wid << 8) + ((u >> shift) & 255u)], 1u);
            }
            __syncthreads();
            unsigned val = 0, s = 0;
            if (tid < 256) {
                for (int w = 0; w < 16; ++w) val += whist[(w << 8) + tid];
                s = val;
#pragma unroll
                for (int off = 1; off < 64; off <<= 1) {
                    unsigned t = __shfl_down(s, off);
                    if (lane + off < 64) s += t;
                }
                if (lane == 0) wtot[wid] = s;
            }
            __syncthreads();
            if (tid < 256) {
                unsigned cge = s;
                for (int w = wid + 1; w < 4; ++w) cge += wtot[w];
                unsigned cgt = cge - val;
                if (cgt < kk && cge >= kk) { sbin = (unsigned)tid; skk = kk - cgt; }
            }
            __syncthreads();
            prefix   |= (sbin << shift);
            maskbits |= (255u << shift);
            kk = skk;
        }
        vstar = prefix;
        rem   = kk;
        e0 = (uu.x == vstar); e1 = (uu.y == vstar);
        e2 = (uu.z == vstar); e3 = (uu.w == vstar);
        cnt = e0 + e1 + e2 + e3;
        inc = cnt;
#pragma unroll
        for (int off = 1; off < 64; off <<= 1) {
            unsigned t = __shfl_up(inc, off);
            if (lane >= off) inc += t;
        }
        __syncthreads();   // protect wsum reuse
        if (lane == 63) wsum[wid] = inc;
        __syncthreads();
        if (wid == 0) {
            unsigned wv = (lane < 16) ? wsum[lane] : 0;
#pragma unroll
            for (int off = 1; off < 16; off <<= 1) {
                unsigned t = __shfl_up(wv, off);
                if (lane >= off) wv += t;
            }
            if (lane < 16) wsum[lane] = wv;
        }
        __syncthreads();
        p = inc - cnt + (wid > 0 ? wsum[wid - 1] : 0);
    }

    // selection: strictly-greater always in; ties by lowest index
    const bool sel0 = (uu.x > vstar) || (e0 && p < rem); p += e0;
    const bool sel1 = (uu.y > vstar) || (e1 && p < rem); p += e1;
    const bool sel2 = (uu.z > vstar) || (e2 && p < rem); p += e2;
    const bool sel3 = (uu.w > vstar) || (e3 && p < rem);

    if (plane == 0) {
        float4 dv = make_float4(sel0 ? 3.0f : 1.0f, sel1 ? 3.0f : 1.0f,
                                sel2 ? 3.0f : 1.0f, sel3 ? 3.0f : 1.0f);
        reinterpret_cast<float4*>(out + (long)b * SS)[tid] = dv;
    } else {
        // masks base is out + B*S + 1 (odd float offset -> scalar stores)
        float* m = out + (long)BB * SS + 1 + (long)plane * BB * SS + (long)b * SS;
        const int base = tid * 4;
        m[base + 0] = sel0 ? 1.0f : 0.0f;
        m[base + 1] = sel1 ? 1.0f : 0.0f;
        m[base + 2] = sel2 ? 1.0f : 0.0f;
        m[base + 3] = sel3 ? 1.0f : 0.0f;
    }
}

extern "C" void kernel_launch(void* const* d_in, const int* in_sizes, int n_in,
                              void* d_out, int out_size, void* d_ws, size_t ws_size,
                              hipStream_t stream) {
    const float* hs    = (const float*)d_in[0];
    const float* theta = (const float*)d_in[1];
    float* out = (float*)d_out;

    float*  scores0  = (float*)d_ws;                                  // 64 KB
    double* partials = (double*)((char*)d_ws + (size_t)BB * SS * 4);  // 96 KB
    float*  m0       = out + (long)BB * SS + 1;                       // masks[0]

    score_kernel <<<dim3(NBLK), dim3(256),  0, stream>>>(hs, theta, scores0, partials, m0);
    select_kernel<<<dim3(13),   dim3(1024), 0, stream>>>(scores0, partials, out);
}